// Round 5
// baseline (238.043 us; speedup 1.0000x reference)
//
#include <hip/hip_runtime.h>
#include <hip/hip_bf16.h>

#define NN   12288
#define EE   393216
#define WELL 128                // ELL slots per row (pow2; max degree ~64)
#define NELL (NN*WELL)
#define BG   16
#define FIN  15
#define FH1  32
#define FH2  64
#define NCL  11
#define BNEPS 1e-5f
#define NBANK 32

typedef unsigned long long u64;
static inline int cdiv(long a, long b){ return (int)((a + b - 1) / b); }

__device__ __forceinline__ int getIdx(const void* p, long i, int is64){
  return is64 ? (int)((const long long*)p)[i] : ((const int*)p)[i];
}

__device__ __forceinline__ float degOf(unsigned lo){
  return 1.0f + (float)lo * (1.0f/1048576.0f);
}

// ---- pre: zero deg_cnt + csp banks + embf; detect int width ----
__global__ void k_pre(u64* deg_cnt, float* csp1, float* csp2, float* csp3,
                      float* embf, const void* ei, const void* batch, int* flags){
  int g = blockIdx.x*256 + threadIdx.x;
  if (g < NN) deg_cnt[g] = 0ull;
  if (g < NBANK*128){ csp1[g] = 0.f; csp2[g] = 0.f; csp3[g] = 0.f; }
  if (g < BG*64) embf[g] = 0.f;          // pool accumulates via atomicMax, vals >= 0
  if (blockIdx.x == 0 && threadIdx.x < 64){
    const int* a = (const int*)ei;
    unsigned long long m0 = __ballot(a[2*threadIdx.x + 1] == 0);
    const int* b = (const int*)batch;
    int j = 96*threadIdx.x;
    unsigned long long m1 = __ballot(b[2*j + 1] == 0);
    if (threadIdx.x == 0){
      flags[0] = (m0 == ~0ull) ? 1 : 0;
      flags[1] = (m1 == ~0ull) ? 1 : 0;
    }
  }
}

// ---- edge pass: ONE u64 atomic per edge; returned count = ELL slot ----
__global__ void k_edge(const float* ea, const float* we, const float* bedg,
                       const void* ei, const int* flags, u64* deg_cnt, u64* csr_p){
  int e = blockIdx.x*256 + threadIdx.x;
  if (e >= EE) return;
  int is64 = flags[0];
  float2 eav = ((const float2*)ea)[e];
  float z = eav.x*we[0] + eav.y*we[1] + bedg[0];
  float w = 1.0f/(1.0f + expf(-z));
  int r = getIdx(ei, e, is64);
  int c = getIdx(ei, (long)EE + e, is64);
  u64 add = (1ull << 32) | (u64)__float2uint_rn(w * 1048576.0f);
  u64 old = atomicAdd(&deg_cnt[r], add);
  int slot = (int)(old >> 32);
  if (slot < WELL)
    csr_p[((long)r << 7) + slot] = (u64)(unsigned)c | ((u64)__float_as_uint(w) << 32);
}

// ---- fused GCN layer, one tile per block, ELL chunks of 16 (issue all 16
// gathers per round -> half the serial L2 round-trips vs chunks of 8).
// deg normalization computed inline from deg_cnt low word (k_dis/k_fix gone).
// BN coefficients computed per-block from csp banks (k_stat eliminated).
template<int F, int FP, int FO, int APPLY_BN>
__global__ void __launch_bounds__(256) k_layer(
    const float* __restrict__ Hin,
    const float* __restrict__ cspin, const float* __restrict__ gam,
    const float* __restrict__ bet,
    const float* __restrict__ W, const float* __restrict__ bias,
    const u64* __restrict__ deg_cnt, const u64* __restrict__ csr_p,
    float* __restrict__ Pout, float* __restrict__ csout){
  const int R = 256/FP;
  __shared__ float At[R][FP];
  __shared__ float lcs[FO], lcq[FO];
  __shared__ float lsc[64], lsh[64];
  if (threadIdx.x < FO){ lcs[threadIdx.x] = 0.f; lcq[threadIdx.x] = 0.f; }
  if (APPLY_BN && threadIdx.x < F){
    float s = 0.f, q = 0.f;
    #pragma unroll
    for (int b = 0; b < NBANK; b++){
      s += cspin[b*128 + threadIdx.x];
      q += cspin[b*128 + 64 + threadIdx.x];
    }
    float mu  = s*(1.0f/NN);
    float var = q*(1.0f/NN) - mu*mu;
    float sc = gam[threadIdx.x]*rsqrtf(var + BNEPS);
    lsc[threadIdx.x] = sc;
    lsh[threadIdx.x] = bet[threadIdx.x] - mu*sc;
  }
  __syncthreads();
  int f = threadIdx.x % FP, lr = threadIdx.x / FP;
  float sc = 1.f, sh = 0.f;
  if (APPLY_BN && f < F){ sc = lsc[f]; sh = lsh[f]; }
  int row = blockIdx.x*R + lr;
  const unsigned* __restrict__ cl = (const unsigned*)deg_cnt;  // low words
  if (f < F){
    u64 dc = deg_cnt[row];
    float d = rsqrtf(degOf((unsigned)(dc & 0xffffffffull)));
    int n = (int)(dc >> 32);
    n = n < WELL ? n : WELL;
    float v0 = Hin[row*F + f];
    if (APPLY_BN) v0 = fmaxf(v0*sc + sh, 0.f);
    float acc = d * v0;                       // self loop
    int nch = (n + 15) >> 4;                  // chunks of 16 slots
    const uint4* pb = (const uint4*)(csr_p + ((long)row << 7));  // 64 uint4
    if (nch > 0){
      uint4 a[8], b[8];
      #pragma unroll
      for (int j = 0; j < 8; j++) a[j] = pb[j];
      for (int ch = 0; ch < nch; ch++){
        bool more = (ch + 1 < nch);
        if (more){
          #pragma unroll
          for (int j = 0; j < 8; j++) b[j] = pb[8*ch + 8 + j];
        }
        int base = ch*16;
        if (base + 16 > n){                   // mask garbage tail slots
          #pragma unroll
          for (int j = 0; j < 8; j++){
            if (base + 2*j     >= n){ a[j].x = 0u; a[j].y = 0u; }
            if (base + 2*j + 1 >= n){ a[j].z = 0u; a[j].w = 0u; }
          }
        }
        #pragma unroll
        for (int j = 0; j < 8; j++){
          int c0 = (int)a[j].x, c1 = (int)a[j].z;
          float w0 = __uint_as_float(a[j].y) * rsqrtf(degOf(cl[2*c0]));
          float w1 = __uint_as_float(a[j].w) * rsqrtf(degOf(cl[2*c1]));
          float h0 = Hin[c0*F + f];
          float h1 = Hin[c1*F + f];
          if (APPLY_BN){
            h0 = fmaxf(h0*sc + sh, 0.f);
            h1 = fmaxf(h1*sc + sh, 0.f);
          }
          acc += w0*h0 + w1*h1;
        }
        if (more){
          #pragma unroll
          for (int j = 0; j < 8; j++) a[j] = b[j];
        }
      }
    }
    At[lr][f] = d * acc;
  }
  __syncthreads();
  const int fo = threadIdx.x % FO;     // 256 % FO == 0
  float bb = bias[fo];
  for (int o = threadIdx.x; o < R*FO; o += 256){
    int l = o / FO;
    float s = bb;
    #pragma unroll
    for (int fi = 0; fi < F; fi++) s += At[l][fi] * W[fi*FO + fo];
    Pout[(blockIdx.x*R + l)*FO + fo] = s;
    atomicAdd(&lcs[fo], s);
    atomicAdd(&lcq[fo], s*s);
  }
  __syncthreads();
  if (threadIdx.x < FO){
    int bank = blockIdx.x & (NBANK-1);
    atomicAdd(&csout[bank*128 + threadIdx.x],      lcs[threadIdx.x]);
    atomicAdd(&csout[bank*128 + 64 + threadIdx.x], lcq[threadIdx.x]);
  }
}

// ---- pool: 16 chunks per graph (256 blocks); inline BN3 prep; atomicMax merge.
// Pooled values >= 0 (relu): int-compare on float bits is monotone; zero-init ok.
__global__ void k_pool(const float* P3, const float* csp, const float* gam,
                       const float* bet, const void* batch, const int* flags,
                       float* embf){
  __shared__ float lsc[64], lsh[64];
  if (threadIdx.x < 64){
    float s = 0.f, q = 0.f;
    #pragma unroll
    for (int b = 0; b < NBANK; b++){
      s += csp[b*128 + threadIdx.x];
      q += csp[b*128 + 64 + threadIdx.x];
    }
    float mu  = s*(1.0f/NN);
    float var = q*(1.0f/NN) - mu*mu;
    float sc = gam[threadIdx.x]*rsqrtf(var + BNEPS);
    lsc[threadIdx.x] = sc;
    lsh[threadIdx.x] = bet[threadIdx.x] - mu*sc;
  }
  __syncthreads();
  int is64 = flags[1];
  int b = blockIdx.x & 15, chunk = blockIdx.x >> 4;
  int lo = 0, hi = NN;
  while (lo < hi){ int m = (lo+hi)>>1; if (getIdx(batch, m, is64) < b) lo = m+1; else hi = m; }
  int start = lo;
  lo = start; hi = NN;
  while (lo < hi){ int m = (lo+hi)>>1; if (getIdx(batch, m, is64) < b+1) lo = m+1; else hi = m; }
  int end = lo;
  int f = threadIdx.x & 63, grp = threadIdx.x >> 6;
  float sc = lsc[f], sh = lsh[f];
  float m = 0.0f;
  for (int i = start + chunk*4 + grp; i < end; i += 64)
    m = fmaxf(m, P3[(long)i*FH2 + f]*sc + sh);
  __shared__ float shm[4][64];
  shm[grp][f] = m;
  __syncthreads();
  if (grp == 0){
    float v = fmaxf(fmaxf(shm[0][f], shm[1][f]), fmaxf(shm[2][f], shm[3][f]));
    atomicMax((int*)&embf[b*64 + f], __float_as_int(v));
  }
}

// ---- head fc1 + BN + relu: wave per column; block 0 also copies emb -> out ----
__global__ void __launch_bounds__(256) k_fcA(const float* embf, const float* wf1,
    const float* bf1, const float* gf1, const float* bef1, float* s1g, float* out){
  if (blockIdx.x == 0){
    #pragma unroll
    for (int i = 0; i < 4; i++)
      out[BG*NCL + i*256 + threadIdx.x] = embf[i*256 + threadIdx.x];
  }
  int c = blockIdx.x*4 + (threadIdx.x >> 6);
  int l = threadIdx.x & 63;
  float wcol = wf1[l*512 + c];
  float z[BG];
  #pragma unroll
  for (int r = 0; r < BG; r++){
    float v = embf[r*64 + l] * wcol;
    #pragma unroll
    for (int off = 32; off > 0; off >>= 1) v += __shfl_down(v, off);
    z[r] = v;                 // valid on lane 0
  }
  if (l == 0){
    float bb = bf1[c];
    float s = 0.f, q = 0.f;
    #pragma unroll
    for (int r = 0; r < BG; r++){ float zr = z[r] + bb; s += zr; q += zr*zr; }
    float mean = s*(1.f/BG), var = q*(1.f/BG) - mean*mean;
    float inv = rsqrtf(var + BNEPS);
    float gg = gf1[c], b2 = bef1[c];
    #pragma unroll
    for (int r = 0; r < BG; r++)
      s1g[r*512 + c] = fmaxf(gg*(z[r] + bb - mean)*inv + b2, 0.f);
  }
}

// ---- head fc2 + BN + relu: wave per column ----
__global__ void __launch_bounds__(256) k_fcB(const float* s1g, const float* wf2,
    const float* bf2, const float* gf2, const float* bef2, float* s2g){
  int c = blockIdx.x*4 + (threadIdx.x >> 6);
  int l = threadIdx.x & 63;
  float wreg[8];
  #pragma unroll
  for (int j = 0; j < 8; j++) wreg[j] = wf2[(l + 64*j)*256 + c];
  float z[BG];
  #pragma unroll
  for (int r = 0; r < BG; r++){
    float v = 0.f;
    #pragma unroll
    for (int j = 0; j < 8; j++) v += s1g[r*512 + l + 64*j] * wreg[j];
    #pragma unroll
    for (int off = 32; off > 0; off >>= 1) v += __shfl_down(v, off);
    z[r] = v;
  }
  if (l == 0){
    float bb = bf2[c];
    float s = 0.f, q = 0.f;
    #pragma unroll
    for (int r = 0; r < BG; r++){ float zr = z[r] + bb; s += zr; q += zr*zr; }
    float mean = s*(1.f/BG), var = q*(1.f/BG) - mean*mean;
    float inv = rsqrtf(var + BNEPS);
    float gg = gf2[c], b2 = bef2[c];
    #pragma unroll
    for (int r = 0; r < BG; r++)
      s2g[r*256 + c] = fmaxf(gg*(z[r] + bb - mean)*inv + b2, 0.f);
  }
}

// ---- head fc3 + log_softmax ----
__global__ void k_fc3(const float* s2g, const float* wf3, const float* bf3, float* out){
  __shared__ float s2[BG*256];
  __shared__ float sl[BG*NCL];
  int t = threadIdx.x;
  for (int i = t; i < BG*256; i += 256) s2[i] = s2g[i];
  __syncthreads();
  if (t < BG*NCL){
    int r = t / NCL, c = t - r*NCL;
    float s = bf3[c];
    for (int k = 0; k < 256; k++) s += s2[r*256 + k]*wf3[k*NCL + c];
    sl[t] = s;
  }
  __syncthreads();
  if (t < BG){
    float m = -1e30f;
    for (int c = 0; c < NCL; c++) m = fmaxf(m, sl[t*NCL + c]);
    float s = 0.f;
    for (int c = 0; c < NCL; c++) s += expf(sl[t*NCL + c] - m);
    float lg = logf(s) + m;
    for (int c = 0; c < NCL; c++) out[t*NCL + c] = sl[t*NCL + c] - lg;
  }
}

extern "C" void kernel_launch(void* const* d_in, const int* in_sizes, int n_in,
                              void* d_out, int out_size, void* d_ws, size_t ws_size,
                              hipStream_t stream){
  const float* x    = (const float*)d_in[0];
  const float* ea   = (const float*)d_in[1];
  const float* we   = (const float*)d_in[2];
  const float* bedg = (const float*)d_in[3];
  const float* w1   = (const float*)d_in[4];  const float* b1  = (const float*)d_in[5];
  const float* g1   = (const float*)d_in[6];  const float* be1 = (const float*)d_in[7];
  const float* w2   = (const float*)d_in[8];  const float* b2  = (const float*)d_in[9];
  const float* g2   = (const float*)d_in[10]; const float* be2 = (const float*)d_in[11];
  const float* w3   = (const float*)d_in[12]; const float* b3  = (const float*)d_in[13];
  const float* g3   = (const float*)d_in[14]; const float* be3 = (const float*)d_in[15];
  const float* wf1  = (const float*)d_in[16]; const float* bf1 = (const float*)d_in[17];
  const float* gf1  = (const float*)d_in[18]; const float* bef1= (const float*)d_in[19];
  const float* wf2  = (const float*)d_in[20]; const float* bf2 = (const float*)d_in[21];
  const float* gf2  = (const float*)d_in[22]; const float* bef2= (const float*)d_in[23];
  const float* wf3  = (const float*)d_in[24]; const float* bf3 = (const float*)d_in[25];
  const void* ei    = d_in[26];
  const void* batch = d_in[27];
  float* out = (float*)d_out;

  u64* wq = (u64*)d_ws;
  u64* deg_cnt = wq; wq += NN;
  u64* csr_p   = wq; wq += NELL;
  float* ws = (float*)wq;
  float* P1    = ws; ws += NN*FH1;
  float* P2    = ws; ws += NN*FH2;
  float* P3    = ws; ws += NN*FH2;
  float* csp1  = ws; ws += NBANK*128;
  float* csp2  = ws; ws += NBANK*128;
  float* csp3  = ws; ws += NBANK*128;
  float* embf  = ws; ws += BG*64;
  float* s1g   = ws; ws += BG*512;
  float* s2g   = ws; ws += BG*256;
  int* flags   = (int*)ws;                   // [0]=ei64 [1]=batch64

  k_pre<<<48, 256, 0, stream>>>(deg_cnt, csp1, csp2, csp3, embf, ei, batch, flags);
  k_edge<<<cdiv(EE,256), 256, 0, stream>>>(ea, we, bedg, ei, flags, deg_cnt, csr_p);

  // layer 1: x(15) -> P1(32)
  k_layer<FIN,16,FH1,0><<<NN/16, 256, 0, stream>>>(x, nullptr, nullptr, nullptr,
      w1, b1, deg_cnt, csr_p, P1, csp1);
  // layer 2: BN1(P1)(32) -> P2(64)   (BN coeffs from csp1 inline)
  k_layer<FH1,32,FH2,1><<<NN/8, 256, 0, stream>>>(P1, csp1, g1, be1,
      w2, b2, deg_cnt, csr_p, P2, csp2);
  // layer 3: BN2(P2)(64) -> P3(64)   (BN coeffs from csp2 inline)
  k_layer<FH2,64,FH2,1><<<NN/4, 256, 0, stream>>>(P2, csp2, g2, be2,
      w3, b3, deg_cnt, csr_p, P3, csp3);

  k_pool<<<256, 256, 0, stream>>>(P3, csp3, g3, be3, batch, flags, embf);
  k_fcA<<<128, 256, 0, stream>>>(embf, wf1, bf1, gf1, bef1, s1g, out);
  k_fcB<<<64, 256, 0, stream>>>(s1g, wf2, bf2, gf2, bef2, s2g);
  k_fc3<<<1, 256, 0, stream>>>(s2g, wf3, bf3, out);
}

// Round 6
// 228.733 us; speedup vs baseline: 1.0407x; 1.0407x over previous
//
#include <hip/hip_runtime.h>
#include <hip/hip_bf16.h>

#define NN   12288
#define EE   393216
#define WELL 128                // ELL slots per row (pow2; max degree ~64)
#define NELL (NN*WELL)
#define BG   16
#define FIN  15
#define FH1  32
#define FH2  64
#define NCL  11
#define BNEPS 1e-5f
#define NBANK 32

typedef unsigned long long u64;
static inline int cdiv(long a, long b){ return (int)((a + b - 1) / b); }

__device__ __forceinline__ int getIdx(const void* p, long i, int is64){
  return is64 ? (int)((const long long*)p)[i] : ((const int*)p)[i];
}

__device__ __forceinline__ float degOf(unsigned lo){
  return 1.0f + (float)lo * (1.0f/1048576.0f);
}

// ---- pre: zero deg_cnt + csp banks + embf; detect int width ----
__global__ void k_pre(u64* deg_cnt, float* csp1, float* csp2, float* csp3,
                      float* embf, const void* ei, const void* batch, int* flags){
  int g = blockIdx.x*256 + threadIdx.x;
  if (g < NN) deg_cnt[g] = 0ull;
  if (g < NBANK*128){ csp1[g] = 0.f; csp2[g] = 0.f; csp3[g] = 0.f; }
  if (g < BG*64) embf[g] = 0.f;          // pool accumulates via atomicMax, vals >= 0
  if (blockIdx.x == 0 && threadIdx.x < 64){
    const int* a = (const int*)ei;
    unsigned long long m0 = __ballot(a[2*threadIdx.x + 1] == 0);
    const int* b = (const int*)batch;
    int j = 96*threadIdx.x;
    unsigned long long m1 = __ballot(b[2*j + 1] == 0);
    if (threadIdx.x == 0){
      flags[0] = (m0 == ~0ull) ? 1 : 0;
      flags[1] = (m1 == ~0ull) ? 1 : 0;
    }
  }
}

// ---- edge pass: ONE u64 atomic per edge; returned count = ELL slot.
// Slot packed to 4 B: col[13:0] | wfix[31:14] (w * 2^17). ----
__global__ void k_edge(const float* ea, const float* we, const float* bedg,
                       const void* ei, const int* flags, u64* deg_cnt,
                       unsigned* csr_p){
  int e = blockIdx.x*256 + threadIdx.x;
  if (e >= EE) return;
  int is64 = flags[0];
  float2 eav = ((const float2*)ea)[e];
  float z = eav.x*we[0] + eav.y*we[1] + bedg[0];
  float w = 1.0f/(1.0f + expf(-z));
  int r = getIdx(ei, e, is64);
  int c = getIdx(ei, (long)EE + e, is64);
  u64 add = (1ull << 32) | (u64)__float2uint_rn(w * 1048576.0f);
  u64 old = atomicAdd(&deg_cnt[r], add);
  int slot = (int)(old >> 32);
  if (slot < WELL){
    unsigned wfix = __float2uint_rn(w * 131072.0f);     // 18-bit fixed, w <= 1
    csr_p[((long)r << 7) + slot] = (unsigned)c | (wfix << 14);
  }
}

// ---- fix2: pre-scale w *= rsqrt(deg[col]) in the packed slots (once per edge,
// removes the per-neighbor deg load from ALL three layers). One wave per row,
// lanes = slots, exact count (max 2 sweeps for n<=128). ----
__global__ void __launch_bounds__(256) k_fix2(const u64* __restrict__ deg_cnt,
                                              unsigned* __restrict__ csr_p){
  int row = blockIdx.x*4 + (threadIdx.x >> 6);
  int lane = threadIdx.x & 63;
  const unsigned* cl = (const unsigned*)deg_cnt;        // low words
  int n = (int)(deg_cnt[row] >> 32);
  n = n < WELL ? n : WELL;
  for (int s = lane; s < n; s += 64){
    long idx = ((long)row << 7) + s;
    unsigned v = csr_p[idx];
    int c = (int)(v & 16383u);
    float w = (float)(v >> 14) * (1.0f/131072.0f);
    w *= rsqrtf(degOf(cl[2*c]));
    csr_p[idx] = (unsigned)c | (__float2uint_rn(w * 131072.0f) << 14);
  }
}

// ---- fused GCN layer: packed 4B slots (pre-scaled weights), chunks of 16,
// unpack-all -> gather-all -> accumulate (max loads in flight per round).
// BN coefficients computed per-block from csp banks (k_stat eliminated).
template<int F, int FP, int FO, int APPLY_BN>
__global__ void __launch_bounds__(256) k_layer(
    const float* __restrict__ Hin,
    const float* __restrict__ cspin, const float* __restrict__ gam,
    const float* __restrict__ bet,
    const float* __restrict__ W, const float* __restrict__ bias,
    const u64* __restrict__ deg_cnt, const unsigned* __restrict__ csr_p,
    float* __restrict__ Pout, float* __restrict__ csout){
  const int R = 256/FP;
  __shared__ float At[R][FP];
  __shared__ float lcs[FO], lcq[FO];
  __shared__ float lsc[64], lsh[64];
  if (threadIdx.x < FO){ lcs[threadIdx.x] = 0.f; lcq[threadIdx.x] = 0.f; }
  if (APPLY_BN && threadIdx.x < F){
    float s = 0.f, q = 0.f;
    #pragma unroll
    for (int b = 0; b < NBANK; b++){
      s += cspin[b*128 + threadIdx.x];
      q += cspin[b*128 + 64 + threadIdx.x];
    }
    float mu  = s*(1.0f/NN);
    float var = q*(1.0f/NN) - mu*mu;
    float sc = gam[threadIdx.x]*rsqrtf(var + BNEPS);
    lsc[threadIdx.x] = sc;
    lsh[threadIdx.x] = bet[threadIdx.x] - mu*sc;
  }
  __syncthreads();
  int f = threadIdx.x % FP, lr = threadIdx.x / FP;
  float sc = 1.f, sh = 0.f;
  if (APPLY_BN && f < F){ sc = lsc[f]; sh = lsh[f]; }
  int row = blockIdx.x*R + lr;
  if (f < F){
    u64 dc = deg_cnt[row];
    float d = rsqrtf(degOf((unsigned)(dc & 0xffffffffull)));
    int n = (int)(dc >> 32);
    n = n < WELL ? n : WELL;
    float v0 = Hin[row*F + f];
    if (APPLY_BN) v0 = fmaxf(v0*sc + sh, 0.f);
    float acc = d * v0;                       // self loop
    int nch = (n + 15) >> 4;                  // chunks of 16 packed slots
    const uint4* pb = (const uint4*)(csr_p + ((long)row << 7));  // 32 uint4/row
    if (nch > 0){
      uint4 a[4], b[4];
      #pragma unroll
      for (int j = 0; j < 4; j++) a[j] = pb[j];
      for (int ch = 0; ch < nch; ch++){
        bool more = (ch + 1 < nch);
        if (more){
          #pragma unroll
          for (int j = 0; j < 4; j++) b[j] = pb[4*ch + 4 + j];
        }
        unsigned pv[16];
        pv[0]=a[0].x; pv[1]=a[0].y; pv[2]=a[0].z; pv[3]=a[0].w;
        pv[4]=a[1].x; pv[5]=a[1].y; pv[6]=a[1].z; pv[7]=a[1].w;
        pv[8]=a[2].x; pv[9]=a[2].y; pv[10]=a[2].z; pv[11]=a[2].w;
        pv[12]=a[3].x; pv[13]=a[3].y; pv[14]=a[3].z; pv[15]=a[3].w;
        int base = ch*16;
        if (base + 16 > n){                   // mask garbage tail slots -> w=0
          #pragma unroll
          for (int j = 0; j < 16; j++) if (base + j >= n) pv[j] = 0u;
        }
        float hh[16];
        #pragma unroll
        for (int j = 0; j < 16; j++)
          hh[j] = Hin[(int)(pv[j] & 16383u)*F + f];
        #pragma unroll
        for (int j = 0; j < 16; j++){
          float h = hh[j];
          if (APPLY_BN) h = fmaxf(h*sc + sh, 0.f);
          acc += (float)(pv[j] >> 14) * (1.0f/131072.0f) * h;
        }
        if (more){
          #pragma unroll
          for (int j = 0; j < 4; j++) a[j] = b[j];
        }
      }
    }
    At[lr][f] = d * acc;
  }
  __syncthreads();
  const int fo = threadIdx.x % FO;     // 256 % FO == 0
  float bb = bias[fo];
  for (int o = threadIdx.x; o < R*FO; o += 256){
    int l = o / FO;
    float s = bb;
    #pragma unroll
    for (int fi = 0; fi < F; fi++) s += At[l][fi] * W[fi*FO + fo];
    Pout[(blockIdx.x*R + l)*FO + fo] = s;
    atomicAdd(&lcs[fo], s);
    atomicAdd(&lcq[fo], s*s);
  }
  __syncthreads();
  if (threadIdx.x < FO){
    int bank = blockIdx.x & (NBANK-1);
    atomicAdd(&csout[bank*128 + threadIdx.x],      lcs[threadIdx.x]);
    atomicAdd(&csout[bank*128 + 64 + threadIdx.x], lcq[threadIdx.x]);
  }
}

// ---- pool: 16 chunks per graph (256 blocks); inline BN3 prep; atomicMax merge.
// Pooled values >= 0 (relu): int-compare on float bits is monotone; zero-init ok.
__global__ void k_pool(const float* P3, const float* csp, const float* gam,
                       const float* bet, const void* batch, const int* flags,
                       float* embf){
  __shared__ float lsc[64], lsh[64];
  if (threadIdx.x < 64){
    float s = 0.f, q = 0.f;
    #pragma unroll
    for (int b = 0; b < NBANK; b++){
      s += csp[b*128 + threadIdx.x];
      q += csp[b*128 + 64 + threadIdx.x];
    }
    float mu  = s*(1.0f/NN);
    float var = q*(1.0f/NN) - mu*mu;
    float sc = gam[threadIdx.x]*rsqrtf(var + BNEPS);
    lsc[threadIdx.x] = sc;
    lsh[threadIdx.x] = bet[threadIdx.x] - mu*sc;
  }
  __syncthreads();
  int is64 = flags[1];
  int b = blockIdx.x & 15, chunk = blockIdx.x >> 4;
  int lo = 0, hi = NN;
  while (lo < hi){ int m = (lo+hi)>>1; if (getIdx(batch, m, is64) < b) lo = m+1; else hi = m; }
  int start = lo;
  lo = start; hi = NN;
  while (lo < hi){ int m = (lo+hi)>>1; if (getIdx(batch, m, is64) < b+1) lo = m+1; else hi = m; }
  int end = lo;
  int f = threadIdx.x & 63, grp = threadIdx.x >> 6;
  float sc = lsc[f], sh = lsh[f];
  float m = 0.0f;
  for (int i = start + chunk*4 + grp; i < end; i += 64)
    m = fmaxf(m, P3[(long)i*FH2 + f]*sc + sh);
  __shared__ float shm[4][64];
  shm[grp][f] = m;
  __syncthreads();
  if (grp == 0){
    float v = fmaxf(fmaxf(shm[0][f], shm[1][f]), fmaxf(shm[2][f], shm[3][f]));
    atomicMax((int*)&embf[b*64 + f], __float_as_int(v));
  }
}

// ---- head fc1 + BN + relu: wave per column; block 0 also copies emb -> out ----
__global__ void __launch_bounds__(256) k_fcA(const float* embf, const float* wf1,
    const float* bf1, const float* gf1, const float* bef1, float* s1g, float* out){
  if (blockIdx.x == 0){
    #pragma unroll
    for (int i = 0; i < 4; i++)
      out[BG*NCL + i*256 + threadIdx.x] = embf[i*256 + threadIdx.x];
  }
  int c = blockIdx.x*4 + (threadIdx.x >> 6);
  int l = threadIdx.x & 63;
  float wcol = wf1[l*512 + c];
  float z[BG];
  #pragma unroll
  for (int r = 0; r < BG; r++){
    float v = embf[r*64 + l] * wcol;
    #pragma unroll
    for (int off = 32; off > 0; off >>= 1) v += __shfl_down(v, off);
    z[r] = v;                 // valid on lane 0
  }
  if (l == 0){
    float bb = bf1[c];
    float s = 0.f, q = 0.f;
    #pragma unroll
    for (int r = 0; r < BG; r++){ float zr = z[r] + bb; s += zr; q += zr*zr; }
    float mean = s*(1.f/BG), var = q*(1.f/BG) - mean*mean;
    float inv = rsqrtf(var + BNEPS);
    float gg = gf1[c], b2 = bef1[c];
    #pragma unroll
    for (int r = 0; r < BG; r++)
      s1g[r*512 + c] = fmaxf(gg*(z[r] + bb - mean)*inv + b2, 0.f);
  }
}

// ---- head fc2 + BN + relu: wave per column ----
__global__ void __launch_bounds__(256) k_fcB(const float* s1g, const float* wf2,
    const float* bf2, const float* gf2, const float* bef2, float* s2g){
  int c = blockIdx.x*4 + (threadIdx.x >> 6);
  int l = threadIdx.x & 63;
  float wreg[8];
  #pragma unroll
  for (int j = 0; j < 8; j++) wreg[j] = wf2[(l + 64*j)*256 + c];
  float z[BG];
  #pragma unroll
  for (int r = 0; r < BG; r++){
    float v = 0.f;
    #pragma unroll
    for (int j = 0; j < 8; j++) v += s1g[r*512 + l + 64*j] * wreg[j];
    #pragma unroll
    for (int off = 32; off > 0; off >>= 1) v += __shfl_down(v, off);
    z[r] = v;
  }
  if (l == 0){
    float bb = bf2[c];
    float s = 0.f, q = 0.f;
    #pragma unroll
    for (int r = 0; r < BG; r++){ float zr = z[r] + bb; s += zr; q += zr*zr; }
    float mean = s*(1.f/BG), var = q*(1.f/BG) - mean*mean;
    float inv = rsqrtf(var + BNEPS);
    float gg = gf2[c], b2 = bef2[c];
    #pragma unroll
    for (int r = 0; r < BG; r++)
      s2g[r*256 + c] = fmaxf(gg*(z[r] + bb - mean)*inv + b2, 0.f);
  }
}

// ---- head fc3 + log_softmax ----
__global__ void k_fc3(const float* s2g, const float* wf3, const float* bf3, float* out){
  __shared__ float s2[BG*256];
  __shared__ float sl[BG*NCL];
  int t = threadIdx.x;
  for (int i = t; i < BG*256; i += 256) s2[i] = s2g[i];
  __syncthreads();
  if (t < BG*NCL){
    int r = t / NCL, c = t - r*NCL;
    float s = bf3[c];
    for (int k = 0; k < 256; k++) s += s2[r*256 + k]*wf3[k*NCL + c];
    sl[t] = s;
  }
  __syncthreads();
  if (t < BG){
    float m = -1e30f;
    for (int c = 0; c < NCL; c++) m = fmaxf(m, sl[t*NCL + c]);
    float s = 0.f;
    for (int c = 0; c < NCL; c++) s += expf(sl[t*NCL + c] - m);
    float lg = logf(s) + m;
    for (int c = 0; c < NCL; c++) out[t*NCL + c] = sl[t*NCL + c] - lg;
  }
}

extern "C" void kernel_launch(void* const* d_in, const int* in_sizes, int n_in,
                              void* d_out, int out_size, void* d_ws, size_t ws_size,
                              hipStream_t stream){
  const float* x    = (const float*)d_in[0];
  const float* ea   = (const float*)d_in[1];
  const float* we   = (const float*)d_in[2];
  const float* bedg = (const float*)d_in[3];
  const float* w1   = (const float*)d_in[4];  const float* b1  = (const float*)d_in[5];
  const float* g1   = (const float*)d_in[6];  const float* be1 = (const float*)d_in[7];
  const float* w2   = (const float*)d_in[8];  const float* b2  = (const float*)d_in[9];
  const float* g2   = (const float*)d_in[10]; const float* be2 = (const float*)d_in[11];
  const float* w3   = (const float*)d_in[12]; const float* b3  = (const float*)d_in[13];
  const float* g3   = (const float*)d_in[14]; const float* be3 = (const float*)d_in[15];
  const float* wf1  = (const float*)d_in[16]; const float* bf1 = (const float*)d_in[17];
  const float* gf1  = (const float*)d_in[18]; const float* bef1= (const float*)d_in[19];
  const float* wf2  = (const float*)d_in[20]; const float* bf2 = (const float*)d_in[21];
  const float* gf2  = (const float*)d_in[22]; const float* bef2= (const float*)d_in[23];
  const float* wf3  = (const float*)d_in[24]; const float* bf3 = (const float*)d_in[25];
  const void* ei    = d_in[26];
  const void* batch = d_in[27];
  float* out = (float*)d_out;

  u64* wq = (u64*)d_ws;
  u64* deg_cnt = wq; wq += NN;
  unsigned* csr_p = (unsigned*)wq; wq += NELL/2;   // packed 4B slots
  float* ws = (float*)wq;
  float* P1    = ws; ws += NN*FH1;
  float* P2    = ws; ws += NN*FH2;
  float* P3    = ws; ws += NN*FH2;
  float* csp1  = ws; ws += NBANK*128;
  float* csp2  = ws; ws += NBANK*128;
  float* csp3  = ws; ws += NBANK*128;
  float* embf  = ws; ws += BG*64;
  float* s1g   = ws; ws += BG*512;
  float* s2g   = ws; ws += BG*256;
  int* flags   = (int*)ws;                   // [0]=ei64 [1]=batch64

  k_pre<<<48, 256, 0, stream>>>(deg_cnt, csp1, csp2, csp3, embf, ei, batch, flags);
  k_edge<<<cdiv(EE,256), 256, 0, stream>>>(ea, we, bedg, ei, flags, deg_cnt, csr_p);
  k_fix2<<<NN/4, 256, 0, stream>>>(deg_cnt, csr_p);

  // layer 1: x(15) -> P1(32)
  k_layer<FIN,16,FH1,0><<<NN/16, 256, 0, stream>>>(x, nullptr, nullptr, nullptr,
      w1, b1, deg_cnt, csr_p, P1, csp1);
  // layer 2: BN1(P1)(32) -> P2(64)   (BN coeffs from csp1 inline)
  k_layer<FH1,32,FH2,1><<<NN/8, 256, 0, stream>>>(P1, csp1, g1, be1,
      w2, b2, deg_cnt, csr_p, P2, csp2);
  // layer 3: BN2(P2)(64) -> P3(64)   (BN coeffs from csp2 inline)
  k_layer<FH2,64,FH2,1><<<NN/4, 256, 0, stream>>>(P2, csp2, g2, be2,
      w3, b3, deg_cnt, csr_p, P3, csp3);

  k_pool<<<256, 256, 0, stream>>>(P3, csp3, g3, be3, batch, flags, embf);
  k_fcA<<<128, 256, 0, stream>>>(embf, wf1, bf1, gf1, bef1, s1g, out);
  k_fcB<<<64, 256, 0, stream>>>(s1g, wf2, bf2, gf2, bef2, s2g);
  k_fc3<<<1, 256, 0, stream>>>(s2g, wf3, bf3, out);
}